// Round 1
// 943.752 us; speedup vs baseline: 1.3503x; 1.3503x over previous
//
#include <hip/hip_runtime.h>
#include <hip/hip_bf16.h>

#define N_ENT_C   100000
#define N_EDGE_C  500000
#define N_SEED_C  10000
#define DIM_C     128

typedef unsigned int   u32;
typedef unsigned short u16;
typedef __attribute__((ext_vector_type(8))) short bf16x8;
typedef __attribute__((ext_vector_type(4))) float f32x4;

__device__ __forceinline__ float bflo(u32 v) { return __uint_as_float(v << 16); }
__device__ __forceinline__ float bfhi(u32 v) { return __uint_as_float(v & 0xFFFF0000u); }
__device__ __forceinline__ u16 f2bf(float f) {       // RNE
  u32 u = __float_as_uint(f);
  u += 0x7FFFu + ((u >> 16) & 1u);
  return (u16)(u >> 16);
}

// Detect whether a "float" input buffer is fp32 (flag=1) or packed bf16 (flag=0).
__global__ void k_detect(const u32* __restrict__ words, int* __restrict__ flag) {
  if (blockIdx.x == 0 && threadIdx.x == 0) {
    int cnt = 0;
    for (int i = 0; i < 64; ++i) {
      u32 e = (words[i] >> 7) & 0xFF;
      cnt += (e < 96) ? 1 : 0;
    }
    *flag = (cnt >= 8) ? 1 : 0;  // 1 = fp32, 0 = bf16
  }
}

__global__ void k_zero_int(int* __restrict__ p, int n) {
  int i = blockIdx.x * 256 + threadIdx.x;
  if (i < n) p[i] = 0;
}

// Batched over both graphs via gridDim.y.
__global__ void k_count(const int2* __restrict__ ea, const int2* __restrict__ eb,
                        int* __restrict__ deg, int E) {
  int e = blockIdx.x * 256 + threadIdx.x;
  if (e >= E) return;
  const int2* ed = blockIdx.y ? eb : ea;
  int* d = deg + blockIdx.y * N_ENT_C;
  int2 v = ed[e];
  atomicAdd(&d[v.x], 1);
  atomicAdd(&d[v.y], 1);
}

__global__ void k_rdeg(const int* __restrict__ deg, float* __restrict__ rdeg, int n) {
  int i = blockIdx.x * 256 + threadIdx.x;
  if (i < n) rdeg[i] = rsqrtf((float)(deg[i] + 1));
}

// ---- 3-kernel exclusive scan of deg[n] -> row_start[n] (n up to 2*N_ENT) ----
__global__ void k_scan1(const int* __restrict__ deg, int* __restrict__ row_start,
                        int* __restrict__ bsum, int n) {
  __shared__ int s[256];
  int b = blockIdx.x, tid = threadIdx.x;
  int i0 = b * 1024 + tid * 4;
  int d0 = (i0 + 0 < n) ? deg[i0 + 0] : 0;
  int d1 = (i0 + 1 < n) ? deg[i0 + 1] : 0;
  int d2 = (i0 + 2 < n) ? deg[i0 + 2] : 0;
  int d3 = (i0 + 3 < n) ? deg[i0 + 3] : 0;
  int tsum = d0 + d1 + d2 + d3;
  s[tid] = tsum;
  __syncthreads();
  for (int off = 1; off < 256; off <<= 1) {
    int v = (tid >= off) ? s[tid - off] : 0;
    __syncthreads();
    s[tid] += v;
    __syncthreads();
  }
  int toff = s[tid] - tsum;
  if (i0 + 0 < n) row_start[i0 + 0] = toff;
  if (i0 + 1 < n) row_start[i0 + 1] = toff + d0;
  if (i0 + 2 < n) row_start[i0 + 2] = toff + d0 + d1;
  if (i0 + 3 < n) row_start[i0 + 3] = toff + d0 + d1 + d2;
  if (tid == 255) bsum[b] = s[255];
}

// Parallel block-sum scan (was a single-thread 98-iter dependent chain ~20+us).
__global__ void k_scan2(int* __restrict__ bsum, int nb) {
  __shared__ int s[256];
  int tid = threadIdx.x;
  int v = (tid < nb) ? bsum[tid] : 0;
  s[tid] = v;
  __syncthreads();
  for (int off = 1; off < 256; off <<= 1) {
    int u = (tid >= off) ? s[tid - off] : 0;
    __syncthreads();
    s[tid] += u;
    __syncthreads();
  }
  if (tid < nb) bsum[tid] = s[tid] - v;   // exclusive
}

__global__ void k_scan3(int* __restrict__ row_start, int* __restrict__ cursor,
                        const int* __restrict__ bsum, int n) {
  int i = blockIdx.x * 256 + threadIdx.x;
  if (i < n) {
    int rs = row_start[i] + bsum[i >> 10];
    row_start[i] = rs;
    cursor[i] = rs;
  }
}

// CSR entries carry {neighbor, rdeg[neighbor]} so the gather has no dependent
// rdeg load (chain csr->xin only). Batched over both graphs via gridDim.y;
// csr2 offsets are absolute (scan ran over the concatenated deg array).
__global__ void k_fill_csr(const int2* __restrict__ ea, const int2* __restrict__ eb,
                           int* __restrict__ cursor, const float* __restrict__ rdeg,
                           int2* __restrict__ csr2, int E) {
  int e = blockIdx.x * 256 + threadIdx.x;
  if (e >= E) return;
  int base = blockIdx.y * N_ENT_C;
  const int2* ed = blockIdx.y ? eb : ea;
  int2 v = ed[e];
  float rx = rdeg[base + v.x], ry = rdeg[base + v.y];
  int p0 = atomicAdd(&cursor[base + v.y], 1);
  csr2[p0] = make_int2(v.x, __float_as_int(rx));
  int p1 = atomicAdd(&cursor[base + v.x], 1);
  csr2[p1] = make_int2(v.y, __float_as_int(ry));
}

// emb (fp32 or bf16 per flag) -> packed bf16 x. Batched: y=0 -> d0, y=1 -> d1.
__global__ void k_cvt_bf16(const void* __restrict__ s0, const void* __restrict__ s1,
                           u32* __restrict__ d0, u32* __restrict__ d1,
                           const int* __restrict__ flag, int n2) {
  int i = blockIdx.x * 256 + threadIdx.x;
  if (i >= n2) return;
  const void* src = blockIdx.y ? s1 : s0;
  u32* dst = blockIdx.y ? d1 : d0;
  if (*flag) {
    float2 v = ((const float2*)src)[i];
    dst[i] = (u32)f2bf(v.x) | ((u32)f2bf(v.y) << 16);
  } else {
    dst[i] = ((const u32*)src)[i];
  }
}

// Fused: per block of 32 rows -> gather+normalize into bf16 A-tile, MFMA with
// W^T (bf16 in LDS), residual + relu, write bf16 x_out.
// x_out = relu( A @ W + x_in ),  A[i,k] = rdeg[i]*sum_nbr + rdeg[i]^2*x_in[i,k]
//
// LDS = 40960 B exactly (was 43520 w/ +8 pad): XOR swizzle replaces the pad so
// 4 blocks/CU fit (4*40960 = 160 KB) -> 16 waves/CU vs 12. Swizzle: 16B slot
// index ^= (row & 7); b128 reads stay at the structural 8-access minimum.
__global__ __launch_bounds__(256, 4) void k_fused(
    const int* __restrict__ row_start, const int* __restrict__ deg,
    const int2* __restrict__ csr2, const u32* __restrict__ xin,
    const float* __restrict__ rdeg, const void* __restrict__ W,
    const int* __restrict__ flag, u32* __restrict__ xout) {
  __shared__ __align__(16) u16 sWt[128 * 128];   // 32768 B, swizzled W^T [n][k]
  __shared__ __align__(16) u16 sA[32 * 128];     //  8192 B, swizzled A-tile

  const int tid = threadIdx.x;
  const int row0 = blockIdx.x * 32;
  const int isf32 = *flag;

  // ---- stage W^T (bf16), swizzled: u32 word (n, k2) at n*64 + (k2 ^ ((n&7)<<2))
  {
    u32* sW32 = (u32*)sWt;
    const float* Wf = (const float*)W;
    const u16*   Wu = (const u16*)W;
    for (int i = tid; i < 64 * 128; i += 256) {
      int k2 = i >> 7;        // pair of k: 2*k2, 2*k2+1
      int n  = i & 127;
      u16 lo, hi;
      if (isf32) { lo = f2bf(Wf[(2 * k2) * 128 + n]); hi = f2bf(Wf[(2 * k2 + 1) * 128 + n]); }
      else       { lo = Wu[(2 * k2) * 128 + n];       hi = Wu[(2 * k2 + 1) * 128 + n]; }
      sW32[n * 64 + (k2 ^ ((n & 7) << 2))] = (u32)lo | ((u32)hi << 16);
    }
  }

  // ---- gather: wave w owns rows row0 + w + 4j. 4-way unroll keeps 4
  // independent 256B xin loads in flight per csr->xin chain traversal.
  const int wave = tid >> 6, lane = tid & 63;
  for (int j = 0; j < 8; ++j) {
    const int rl = wave + 4 * j;
    const int row = row0 + rl;
    const int rs = row_start[row];
    const int de = deg[row];
    const float rd = rdeg[row];
    const u32 vs = xin[((u32)row << 6) | lane];   // self term, issued early
    const int2* cp = csr2 + rs;
    float a0 = 0.f, a1 = 0.f;
    int t = 0;
    for (; t + 3 < de; t += 4) {
      int2 e0 = cp[t], e1 = cp[t + 1], e2 = cp[t + 2], e3 = cp[t + 3];
      u32 v0 = xin[((u32)e0.x << 6) | lane];
      u32 v1 = xin[((u32)e1.x << 6) | lane];
      u32 v2 = xin[((u32)e2.x << 6) | lane];
      u32 v3 = xin[((u32)e3.x << 6) | lane];
      float r0 = __int_as_float(e0.y), r1 = __int_as_float(e1.y);
      float r2 = __int_as_float(e2.y), r3 = __int_as_float(e3.y);
      a0 += r0 * bflo(v0) + r1 * bflo(v1) + r2 * bflo(v2) + r3 * bflo(v3);
      a1 += r0 * bfhi(v0) + r1 * bfhi(v1) + r2 * bfhi(v2) + r3 * bfhi(v3);
    }
    int rem = de - t;
    if (rem & 2) {
      int2 e0 = cp[t], e1 = cp[t + 1];
      u32 v0 = xin[((u32)e0.x << 6) | lane];
      u32 v1 = xin[((u32)e1.x << 6) | lane];
      float r0 = __int_as_float(e0.y), r1 = __int_as_float(e1.y);
      a0 += r0 * bflo(v0) + r1 * bflo(v1);
      a1 += r0 * bfhi(v0) + r1 * bfhi(v1);
      t += 2;
    }
    if (rem & 1) {
      int2 e0 = cp[t];
      u32 v0 = xin[((u32)e0.x << 6) | lane];
      float r0 = __int_as_float(e0.y);
      a0 += r0 * bflo(v0);
      a1 += r0 * bfhi(v0);
    }
    a0 = rd * a0 + rd * rd * bflo(vs);
    a1 = rd * a1 + rd * rd * bfhi(vs);
    ((u32*)sA)[rl * 64 + (lane ^ ((rl & 7) << 2))] = (u32)f2bf(a0) | ((u32)f2bf(a1) << 16);
  }
  __syncthreads();

  // ---- MFMA: wave -> 16 rows x 64 cols ----
  const int rows_h = (wave >> 1) * 16;   // 0 | 16  (multiple of 16 -> row&7 == m&7)
  const int col_q  = (wave & 1) * 64;    // 0 | 64  (col row &7 == m&7 too)
  const int m = lane & 15, q = lane >> 4;
  f32x4 acc[4];
  for (int ct = 0; ct < 4; ++ct) acc[ct] = (f32x4){0.f, 0.f, 0.f, 0.f};
#pragma unroll
  for (int kt = 0; kt < 4; ++kt) {
    int k0 = kt * 32 + q * 8;
    int ks = k0 ^ ((m & 7) << 3);        // same swizzle for A row and W^T rows
    bf16x8 a = *(const bf16x8*)&sA[(rows_h + m) * 128 + ks];
#pragma unroll
    for (int ct = 0; ct < 4; ++ct) {
      bf16x8 b = *(const bf16x8*)&sWt[(col_q + ct * 16 + m) * 128 + ks];
      acc[ct] = __builtin_amdgcn_mfma_f32_16x16x32_bf16(a, b, acc[ct], 0, 0, 0);
    }
  }
  __syncthreads();   // all waves done reading sWt/sA before C overwrites sWt

  // ---- C (fp32) into LDS for coalesced epilogue ----
  float* sC = (float*)sWt;               // 32 x 132 fp32 = 16896 B
#pragma unroll
  for (int ct = 0; ct < 4; ++ct)
#pragma unroll
    for (int r = 0; r < 4; ++r)
      sC[(rows_h + q * 4 + r) * 132 + (col_q + ct * 16 + m)] = acc[ct][r];
  __syncthreads();

  // ---- epilogue: +residual, relu, pack bf16, coalesced store ----
  {
    int rowl = tid >> 3;
    int c0 = (tid & 7) * 16;
    size_t goff = (size_t)(row0 + rowl) * 64 + (c0 >> 1);  // in u32 units
    const u32* resp = xin + goff;
    u32 ov[8];
#pragma unroll
    for (int u = 0; u < 8; ++u) {
      u32 rv = resp[u];
      float lo = fmaxf(sC[rowl * 132 + c0 + 2 * u]     + bflo(rv), 0.f);
      float hi = fmaxf(sC[rowl * 132 + c0 + 2 * u + 1] + bfhi(rv), 0.f);
      ov[u] = (u32)f2bf(lo) | ((u32)f2bf(hi) << 16);
    }
    uint4* op = (uint4*)(xout + goff);
    op[0] = make_uint4(ov[0], ov[1], ov[2], ov[3]);
    op[1] = make_uint4(ov[4], ov[5], ov[6], ov[7]);
  }
}

// Batched outputs: y=0 -> graph sr (from xa), y=1 -> graph tg (from xb).
__global__ void k_out_ent(const u32* __restrict__ xa, const u32* __restrict__ xb,
                          float2* __restrict__ oa, float2* __restrict__ ob, int n2) {
  int i = blockIdx.x * 256 + threadIdx.x;
  if (i >= n2) return;
  const u32* x = blockIdx.y ? xb : xa;
  float2* o = blockIdx.y ? ob : oa;
  u32 v = x[i];
  o[i] = make_float2(bflo(v), bfhi(v));
}

__global__ void k_out_seed(const u32* __restrict__ xa, const u32* __restrict__ xb,
                           const int* __restrict__ sa, const int* __restrict__ sb,
                           float2* __restrict__ oa, float2* __restrict__ ob, int total2) {
  int t = blockIdx.x * 256 + threadIdx.x;
  if (t >= total2) return;
  const u32* x = blockIdx.y ? xb : xa;
  const int* seeds = blockIdx.y ? sb : sa;
  float2* o = blockIdx.y ? ob : oa;
  int s = t >> 6, w = t & 63;
  u32 v = x[((u32)seeds[s] << 6) | w];
  o[t] = make_float2(bflo(v), bfhi(v));
}

extern "C" void kernel_launch(void* const* d_in, const int* in_sizes, int n_in,
                              void* d_out, int out_size, void* d_ws, size_t ws_size,
                              hipStream_t stream) {
  const int*  sr_seeds = (const int*)d_in[0];
  const int*  tg_seeds = (const int*)d_in[1];
  // d_in[2], d_in[3]: triples_* — unused by the reference.
  const void* emb_sr   = d_in[4];
  const void* emb_tg   = d_in[5];
  const int*  edges_sr = (const int*)d_in[6];
  const int*  edges_tg = (const int*)d_in[7];
  const void* W1       = d_in[8];
  const void* W2       = d_in[9];
  float* out = (float*)d_out;

  const int nd = N_ENT_C * DIM_C;  // 12,800,000
  const int N2 = 2 * N_ENT_C;      // 200,000 (both graphs concatenated)

  // ws layout (~96 MB of >=102.8 MB proven):
  u16* x_A       = (u16*)d_ws;                    // 25.6 MB (sr pipeline / result)
  u16* x_B       = x_A + (size_t)nd;              // 25.6 MB (tg pipeline / result)
  u16* x_C       = x_B + (size_t)nd;              // 25.6 MB (layer scratch)
  float* ws_rdeg = (float*)(x_C + (size_t)nd);    // 800 KB (2N)
  int* ws_flag   = (int*)(ws_rdeg + N2);          // 256 B
  int* deg       = ws_flag + 64;                  // 800 KB (2N)
  int* row_start = deg + N2;                      // 800 KB (2N, absolute csr2 offsets)
  int* cursor    = row_start + N2;                // 800 KB (2N)
  int* bsum      = cursor + N2;                   // 4 KB
  int2* csr2     = (int2*)(bsum + 1024);          // 16 MB  (2M entries {nbr, rdeg})

  float* out_seed_sr = out;
  float* out_seed_tg = out + (size_t)N_SEED_C * DIM_C;
  float* out_ent_sr  = out + (size_t)2 * N_SEED_C * DIM_C;
  float* out_ent_tg  = out_ent_sr + (size_t)nd;

  k_detect<<<1, 64, 0, stream>>>((const u32*)emb_sr, ws_flag);

  // ---- CSR build for BOTH graphs in one set of dispatches ----
  const int NB_SCAN = (N2 + 1023) / 1024;  // 196
  dim3 egrid((N_EDGE_C + 255) / 256, 2);
  k_zero_int<<<(N2 + 255) / 256, 256, 0, stream>>>(deg, N2);
  k_count   <<<egrid, 256, 0, stream>>>((const int2*)edges_sr, (const int2*)edges_tg, deg, N_EDGE_C);
  k_rdeg    <<<(N2 + 255) / 256, 256, 0, stream>>>(deg, ws_rdeg, N2);
  k_scan1   <<<NB_SCAN, 256, 0, stream>>>(deg, row_start, bsum, N2);
  k_scan2   <<<1, 256, 0, stream>>>(bsum, NB_SCAN);
  k_scan3   <<<(N2 + 255) / 256, 256, 0, stream>>>(row_start, cursor, bsum, N2);
  k_fill_csr<<<egrid, 256, 0, stream>>>((const int2*)edges_sr, (const int2*)edges_tg,
                                        cursor, ws_rdeg, csr2, N_EDGE_C);

  // ---- embeddings -> bf16 (both graphs, one dispatch) ----
  dim3 cgrid((nd / 2 + 255) / 256, 2);
  k_cvt_bf16<<<cgrid, 256, 0, stream>>>(emb_sr, emb_tg, (u32*)x_A, (u32*)x_B, ws_flag, nd / 2);

  // ---- 2 fused GCN layers per graph ----
  // sr: A -> C -> A
  k_fused<<<N_ENT_C / 32, 256, 0, stream>>>(row_start, deg, csr2, (const u32*)x_A,
                                            ws_rdeg, W1, ws_flag, (u32*)x_C);
  k_fused<<<N_ENT_C / 32, 256, 0, stream>>>(row_start, deg, csr2, (const u32*)x_C,
                                            ws_rdeg, W2, ws_flag, (u32*)x_A);
  // tg: B -> C -> B  (sections of the concatenated arrays; csr2 offsets absolute)
  k_fused<<<N_ENT_C / 32, 256, 0, stream>>>(row_start + N_ENT_C, deg + N_ENT_C, csr2,
                                            (const u32*)x_B, ws_rdeg + N_ENT_C, W1, ws_flag, (u32*)x_C);
  k_fused<<<N_ENT_C / 32, 256, 0, stream>>>(row_start + N_ENT_C, deg + N_ENT_C, csr2,
                                            (const u32*)x_C, ws_rdeg + N_ENT_C, W2, ws_flag, (u32*)x_B);

  // ---- outputs (both graphs, batched) ----
  dim3 ogrid((nd / 2 + 255) / 256, 2);
  k_out_ent<<<ogrid, 256, 0, stream>>>((const u32*)x_A, (const u32*)x_B,
                                       (float2*)out_ent_sr, (float2*)out_ent_tg, nd / 2);
  dim3 sgrid((N_SEED_C * 64 + 255) / 256, 2);
  k_out_seed<<<sgrid, 256, 0, stream>>>((const u32*)x_A, (const u32*)x_B, sr_seeds, tg_seeds,
                                        (float2*)out_seed_sr, (float2*)out_seed_tg, N_SEED_C * 64);
}

// Round 2
// 732.581 us; speedup vs baseline: 1.7395x; 1.2883x over previous
//
#include <hip/hip_runtime.h>
#include <hip/hip_bf16.h>

#define N_ENT_C   100000
#define N_EDGE_C  500000
#define N_SEED_C  10000
#define DIM_C     128

#define N2_C      (2 * N_ENT_C)     // concat rows (both graphs)
#define NBKT      391               // ceil(N2 / 512)
#define BKT_CAP   8192              // entries per bucket (mean 5120, 43 sigma safe)
#define EPB       4096              // edges per block in phase A

typedef unsigned int   u32;
typedef unsigned short u16;
typedef __attribute__((ext_vector_type(8))) short bf16x8;
typedef __attribute__((ext_vector_type(4))) float f32x4;

__device__ __forceinline__ float bflo(u32 v) { return __uint_as_float(v << 16); }
__device__ __forceinline__ float bfhi(u32 v) { return __uint_as_float(v & 0xFFFF0000u); }
__device__ __forceinline__ u16 f2bf(float f) {       // RNE
  u32 u = __float_as_uint(f);
  u += 0x7FFFu + ((u >> 16) & 1u);
  return (u16)(u >> 16);
}

// Detect fp32 vs packed bf16 input; also zero the bucket counters.
__global__ void k_detect(const u32* __restrict__ words, int* __restrict__ flag,
                         int* __restrict__ bkt_cnt) {
  int tid = threadIdx.x;
  bkt_cnt[tid] = 0;
  bkt_cnt[tid + 256] = 0;
  if (tid == 0) {
    int cnt = 0;
    for (int i = 0; i < 64; ++i) {
      u32 e = (words[i] >> 7) & 0xFF;
      cnt += (e < 96) ? 1 : 0;
    }
    *flag = (cnt >= 8) ? 1 : 0;  // 1 = fp32, 0 = bf16
  }
}

// ---- Phase A: bin edge entries by 512-row bucket into csr_tmp ----
// Entry: u32 = src | (dlocal << 20); dlocal = concat_row & 511 (9 bits), src < 2^17.
// LDS binning gives ~21-entry contiguous runs per (block,bucket) -> low write amp.
__global__ __launch_bounds__(256, 2) void k_fill_binned(
    const int2* __restrict__ ea, const int2* __restrict__ eb,
    int* __restrict__ bkt_cnt, u32* __restrict__ csr_tmp, int E) {
  __shared__ u32 ein[2 * EPB];        // 32 KB
  __shared__ u16 ebkt[2 * EPB];       // 16 KB
  __shared__ int lcount[512];         // counts, then cursors
  __shared__ int lstart[513];
  __shared__ int gbase[512];
  __shared__ int ssc[256];

  const int tid = threadIdx.x;
  const int gofs = blockIdx.y ? N_ENT_C : 0;
  const int2* ed = blockIdx.y ? eb : ea;
  const int e0 = blockIdx.x * EPB;

  lcount[tid] = 0; lcount[tid + 256] = 0;
  __syncthreads();

  int2 ev[16];
#pragma unroll
  for (int i = 0; i < 16; ++i) {
    int e = e0 + tid + i * 256;
    int2 v = (e < E) ? ed[e] : make_int2(0, 0);
    ev[i] = v;
    if (e < E) {
      atomicAdd(&lcount[(gofs + v.y) >> 9], 1);
      atomicAdd(&lcount[(gofs + v.x) >> 9], 1);
    }
  }
  __syncthreads();

  // exclusive scan of lcount[0..511] (2 elems/thread)
  int a = lcount[2 * tid], b = lcount[2 * tid + 1];
  int ts = a + b;
  ssc[tid] = ts;
  __syncthreads();
  for (int off = 1; off < 256; off <<= 1) {
    int v = (tid >= off) ? ssc[tid - off] : 0;
    __syncthreads();
    ssc[tid] += v;
    __syncthreads();
  }
  int ex = ssc[tid] - ts;
  lstart[2 * tid] = ex;
  lstart[2 * tid + 1] = ex + a;
  if (tid == 255) lstart[512] = ssc[255];
  __syncthreads();

  // reserve global bucket ranges (one atomic per non-empty bucket) + init cursors
  {
    int b0 = 2 * tid, b1 = 2 * tid + 1;
    if (b0 < NBKT) { int c = lstart[b0 + 1] - lstart[b0]; gbase[b0] = c ? atomicAdd(&bkt_cnt[b0], c) : 0; }
    if (b1 < NBKT) { int c = lstart[b1 + 1] - lstart[b1]; gbase[b1] = c ? atomicAdd(&bkt_cnt[b1], c) : 0; }
    lcount[tid] = lstart[tid];
    lcount[tid + 256] = lstart[tid + 256];
  }
  __syncthreads();

  // place entries into LDS grouped by bucket
#pragma unroll
  for (int i = 0; i < 16; ++i) {
    int e = e0 + tid + i * 256;
    if (e >= E) continue;
    int2 v = ev[i];
    int r1 = gofs + v.y;
    u32 w1 = (u32)v.x | ((u32)(r1 & 511) << 20);
    int bk1 = r1 >> 9;
    int p = atomicAdd(&lcount[bk1], 1);
    ein[p] = w1; ebkt[p] = (u16)bk1;
    int r2 = gofs + v.x;
    u32 w2 = (u32)v.y | ((u32)(r2 & 511) << 20);
    int bk2 = r2 >> 9;
    p = atomicAdd(&lcount[bk2], 1);
    ein[p] = w2; ebkt[p] = (u16)bk2;
  }
  __syncthreads();

  // copy out: contiguous runs per bucket
  int tot = lstart[512];
  for (int j = tid; j < tot; j += 256) {
    int bk = ebkt[j];
    u32 off = (u32)(gbase[bk] + (j - lstart[bk]));
    if (off < BKT_CAP) csr_tmp[(size_t)bk * BKT_CAP + off] = ein[j];
  }
}

// ---- Phase B1: per-bucket row counts -> deg + rdeg (coalesced, no global atomics)
__global__ void k_deg(const u32* __restrict__ csr_tmp, const int* __restrict__ bkt_cnt,
                      int* __restrict__ deg, float* __restrict__ rdeg) {
  __shared__ int lcnt[512];
  int bk = blockIdx.x, tid = threadIdx.x;
  lcnt[tid] = 0; lcnt[tid + 256] = 0;
  __syncthreads();
  int cnt = min(bkt_cnt[bk], BKT_CAP);
  const u32* src = csr_tmp + (size_t)bk * BKT_CAP;
  for (int j = tid; j < cnt; j += 256)
    atomicAdd(&lcnt[(src[j] >> 20) & 511], 1);
  __syncthreads();
  int rb0 = bk << 9;
  for (int r = tid; r < 512; r += 256) {
    int row = rb0 + r;
    if (row < N2_C) {
      int d = lcnt[r];
      deg[row] = d;
      rdeg[row] = rsqrtf((float)(d + 1));
    }
  }
}

// ---- 3-kernel exclusive scan of deg[n] -> row_start[n] ----
__global__ void k_scan1(const int* __restrict__ deg, int* __restrict__ row_start,
                        int* __restrict__ bsum, int n) {
  __shared__ int s[256];
  int b = blockIdx.x, tid = threadIdx.x;
  int i0 = b * 1024 + tid * 4;
  int d0 = (i0 + 0 < n) ? deg[i0 + 0] : 0;
  int d1 = (i0 + 1 < n) ? deg[i0 + 1] : 0;
  int d2 = (i0 + 2 < n) ? deg[i0 + 2] : 0;
  int d3 = (i0 + 3 < n) ? deg[i0 + 3] : 0;
  int tsum = d0 + d1 + d2 + d3;
  s[tid] = tsum;
  __syncthreads();
  for (int off = 1; off < 256; off <<= 1) {
    int v = (tid >= off) ? s[tid - off] : 0;
    __syncthreads();
    s[tid] += v;
    __syncthreads();
  }
  int toff = s[tid] - tsum;
  if (i0 + 0 < n) row_start[i0 + 0] = toff;
  if (i0 + 1 < n) row_start[i0 + 1] = toff + d0;
  if (i0 + 2 < n) row_start[i0 + 2] = toff + d0 + d1;
  if (i0 + 3 < n) row_start[i0 + 3] = toff + d0 + d1 + d2;
  if (tid == 255) bsum[b] = s[255];
}

__global__ void k_scan2(int* __restrict__ bsum, int nb) {
  __shared__ int s[256];
  int tid = threadIdx.x;
  int v = (tid < nb) ? bsum[tid] : 0;
  s[tid] = v;
  __syncthreads();
  for (int off = 1; off < 256; off <<= 1) {
    int u = (tid >= off) ? s[tid - off] : 0;
    __syncthreads();
    s[tid] += u;
    __syncthreads();
  }
  if (tid < nb) bsum[tid] = s[tid] - v;   // exclusive
}

__global__ void k_scan3(int* __restrict__ row_start, const int* __restrict__ bsum, int n) {
  int i = blockIdx.x * 256 + threadIdx.x;
  if (i < n) row_start[i] += bsum[i >> 10];
}

// ---- Phase B2: sort each bucket into final CSR {src, rdeg[src]} via LDS cursors.
// Scattered writes stay within one ~40 KB L2-hot region per block.
__global__ void k_csr_sort(const u32* __restrict__ csr_tmp, const int* __restrict__ bkt_cnt,
                           const int* __restrict__ row_start, const float* __restrict__ rdeg,
                           int2* __restrict__ csr) {
  __shared__ int lcur[512];
  int bk = blockIdx.x, tid = threadIdx.x;
  int rb0 = bk << 9;
  int base = row_start[rb0];
  for (int r = tid; r < 512; r += 256) {
    int row = rb0 + r;
    lcur[r] = (row < N2_C) ? row_start[row] - base : 0;
  }
  __syncthreads();
  int cnt = min(bkt_cnt[bk], BKT_CAP);
  const u32* srcp = csr_tmp + (size_t)bk * BKT_CAP;
  for (int j = tid; j < cnt; j += 256) {
    u32 w = srcp[j];
    int dl = (w >> 20) & 511;
    int s = w & 0x1FFFF;
    int pos = atomicAdd(&lcur[dl], 1);
    float r = rdeg[((rb0 + dl) >= N_ENT_C ? N_ENT_C : 0) + s];
    csr[base + pos] = make_int2(s, __float_as_int(r));
  }
}

// emb (fp32 or bf16 per flag) -> packed bf16 x. Batched: y=0 -> d0, y=1 -> d1.
__global__ void k_cvt_bf16(const void* __restrict__ s0, const void* __restrict__ s1,
                           u32* __restrict__ d0, u32* __restrict__ d1,
                           const int* __restrict__ flag, int n2) {
  int i = blockIdx.x * 256 + threadIdx.x;
  if (i >= n2) return;
  const void* src = blockIdx.y ? s1 : s0;
  u32* dst = blockIdx.y ? d1 : d0;
  if (*flag) {
    float2 v = ((const float2*)src)[i];
    dst[i] = (u32)f2bf(v.x) | ((u32)f2bf(v.y) << 16);
  } else {
    dst[i] = ((const u32*)src)[i];
  }
}

// Fused GCN layer, both graphs in one dispatch (blockIdx.y selects graph).
// x_out = relu( A @ W + x_in ),  A[i,k] = rdeg[i]*sum_nbr + rdeg[i]^2*x_in[i,k]
// LDS = 40960 B exactly -> 4 blocks/CU (16 waves/CU). XOR swizzle in place of pad.
__global__ __launch_bounds__(256, 4) void k_fused(
    const int* __restrict__ row_start, const int* __restrict__ deg,
    const int2* __restrict__ csr2, const u32* __restrict__ xin0,
    const u32* __restrict__ xin1, const float* __restrict__ rdeg,
    const void* __restrict__ W, const int* __restrict__ flag,
    u32* __restrict__ xout0, u32* __restrict__ xout1) {
  __shared__ __align__(16) u16 sWt[128 * 128];   // 32768 B, swizzled W^T [n][k]
  __shared__ __align__(16) u16 sA[32 * 128];     //  8192 B, swizzled A-tile

  const int tid = threadIdx.x;
  const int row0 = blockIdx.x * 32;
  const int gofs = blockIdx.y * N_ENT_C;
  const u32* __restrict__ xin  = blockIdx.y ? xin1  : xin0;
  u32* __restrict__ xout       = blockIdx.y ? xout1 : xout0;
  const int* rsb = row_start + gofs;
  const int* dgb = deg + gofs;
  const float* rdb = rdeg + gofs;
  const int isf32 = *flag;

  // ---- stage W^T (bf16), swizzled: u32 word (n, k2) at n*64 + (k2 ^ ((n&7)<<2))
  {
    u32* sW32 = (u32*)sWt;
    const float* Wf = (const float*)W;
    const u16*   Wu = (const u16*)W;
    for (int i = tid; i < 64 * 128; i += 256) {
      int k2 = i >> 7;        // pair of k: 2*k2, 2*k2+1
      int n  = i & 127;
      u16 lo, hi;
      if (isf32) { lo = f2bf(Wf[(2 * k2) * 128 + n]); hi = f2bf(Wf[(2 * k2 + 1) * 128 + n]); }
      else       { lo = Wu[(2 * k2) * 128 + n];       hi = Wu[(2 * k2 + 1) * 128 + n]; }
      sW32[n * 64 + (k2 ^ ((n & 7) << 2))] = (u32)lo | ((u32)hi << 16);
    }
  }

  // ---- gather: wave w owns rows row0 + w + 4j, 4-way unrolled for MLP ----
  const int wave = tid >> 6, lane = tid & 63;
  for (int j = 0; j < 8; ++j) {
    const int rl = wave + 4 * j;
    const int row = row0 + rl;
    const int rs = rsb[row];
    const int de = dgb[row];
    const float rd = rdb[row];
    const u32 vs = xin[((u32)row << 6) | lane];   // self term, issued early
    const int2* cp = csr2 + rs;
    float a0 = 0.f, a1 = 0.f;
    int t = 0;
    for (; t + 3 < de; t += 4) {
      int2 e0 = cp[t], e1 = cp[t + 1], e2 = cp[t + 2], e3 = cp[t + 3];
      u32 v0 = xin[((u32)e0.x << 6) | lane];
      u32 v1 = xin[((u32)e1.x << 6) | lane];
      u32 v2 = xin[((u32)e2.x << 6) | lane];
      u32 v3 = xin[((u32)e3.x << 6) | lane];
      float r0 = __int_as_float(e0.y), r1 = __int_as_float(e1.y);
      float r2 = __int_as_float(e2.y), r3 = __int_as_float(e3.y);
      a0 += r0 * bflo(v0) + r1 * bflo(v1) + r2 * bflo(v2) + r3 * bflo(v3);
      a1 += r0 * bfhi(v0) + r1 * bfhi(v1) + r2 * bfhi(v2) + r3 * bfhi(v3);
    }
    int rem = de - t;
    if (rem & 2) {
      int2 e0 = cp[t], e1 = cp[t + 1];
      u32 v0 = xin[((u32)e0.x << 6) | lane];
      u32 v1 = xin[((u32)e1.x << 6) | lane];
      float r0 = __int_as_float(e0.y), r1 = __int_as_float(e1.y);
      a0 += r0 * bflo(v0) + r1 * bflo(v1);
      a1 += r0 * bfhi(v0) + r1 * bfhi(v1);
      t += 2;
    }
    if (rem & 1) {
      int2 e0 = cp[t];
      u32 v0 = xin[((u32)e0.x << 6) | lane];
      float r0 = __int_as_float(e0.y);
      a0 += r0 * bflo(v0);
      a1 += r0 * bfhi(v0);
    }
    a0 = rd * a0 + rd * rd * bflo(vs);
    a1 = rd * a1 + rd * rd * bfhi(vs);
    ((u32*)sA)[rl * 64 + (lane ^ ((rl & 7) << 2))] = (u32)f2bf(a0) | ((u32)f2bf(a1) << 16);
  }
  __syncthreads();

  // ---- MFMA: wave -> 16 rows x 64 cols ----
  const int rows_h = (wave >> 1) * 16;   // 0 | 16
  const int col_q  = (wave & 1) * 64;    // 0 | 64
  const int m = lane & 15, q = lane >> 4;
  f32x4 acc[4];
  for (int ct = 0; ct < 4; ++ct) acc[ct] = (f32x4){0.f, 0.f, 0.f, 0.f};
#pragma unroll
  for (int kt = 0; kt < 4; ++kt) {
    int k0 = kt * 32 + q * 8;
    int ks = k0 ^ ((m & 7) << 3);        // same swizzle for A row and W^T rows
    bf16x8 a = *(const bf16x8*)&sA[(rows_h + m) * 128 + ks];
#pragma unroll
    for (int ct = 0; ct < 4; ++ct) {
      bf16x8 b = *(const bf16x8*)&sWt[(col_q + ct * 16 + m) * 128 + ks];
      acc[ct] = __builtin_amdgcn_mfma_f32_16x16x32_bf16(a, b, acc[ct], 0, 0, 0);
    }
  }
  __syncthreads();   // all waves done reading sWt/sA before C overwrites sWt

  // ---- C (fp32) into LDS for coalesced epilogue ----
  float* sC = (float*)sWt;               // 32 x 132 fp32 = 16896 B
#pragma unroll
  for (int ct = 0; ct < 4; ++ct)
#pragma unroll
    for (int r = 0; r < 4; ++r)
      sC[(rows_h + q * 4 + r) * 132 + (col_q + ct * 16 + m)] = acc[ct][r];
  __syncthreads();

  // ---- epilogue: +residual, relu, pack bf16, coalesced store ----
  {
    int rowl = tid >> 3;
    int c0 = (tid & 7) * 16;
    size_t goff = (size_t)(row0 + rowl) * 64 + (c0 >> 1);  // in u32 units
    const u32* resp = xin + goff;
    u32 ov[8];
#pragma unroll
    for (int u = 0; u < 8; ++u) {
      u32 rv = resp[u];
      float lo = fmaxf(sC[rowl * 132 + c0 + 2 * u]     + bflo(rv), 0.f);
      float hi = fmaxf(sC[rowl * 132 + c0 + 2 * u + 1] + bfhi(rv), 0.f);
      ov[u] = (u32)f2bf(lo) | ((u32)f2bf(hi) << 16);
    }
    uint4* op = (uint4*)(xout + goff);
    op[0] = make_uint4(ov[0], ov[1], ov[2], ov[3]);
    op[1] = make_uint4(ov[4], ov[5], ov[6], ov[7]);
  }
}

// Batched outputs: y=0 -> graph sr (from xa), y=1 -> graph tg (from xb).
__global__ void k_out_ent(const u32* __restrict__ xa, const u32* __restrict__ xb,
                          float2* __restrict__ oa, float2* __restrict__ ob, int n2) {
  int i = blockIdx.x * 256 + threadIdx.x;
  if (i >= n2) return;
  const u32* x = blockIdx.y ? xb : xa;
  float2* o = blockIdx.y ? ob : oa;
  u32 v = x[i];
  o[i] = make_float2(bflo(v), bfhi(v));
}

__global__ void k_out_seed(const u32* __restrict__ xa, const u32* __restrict__ xb,
                           const int* __restrict__ sa, const int* __restrict__ sb,
                           float2* __restrict__ oa, float2* __restrict__ ob, int total2) {
  int t = blockIdx.x * 256 + threadIdx.x;
  if (t >= total2) return;
  const u32* x = blockIdx.y ? xb : xa;
  const int* seeds = blockIdx.y ? sb : sa;
  float2* o = blockIdx.y ? ob : oa;
  int s = t >> 6, w = t & 63;
  u32 v = x[((u32)seeds[s] << 6) | w];
  o[t] = make_float2(bflo(v), bfhi(v));
}

extern "C" void kernel_launch(void* const* d_in, const int* in_sizes, int n_in,
                              void* d_out, int out_size, void* d_ws, size_t ws_size,
                              hipStream_t stream) {
  const int*  sr_seeds = (const int*)d_in[0];
  const int*  tg_seeds = (const int*)d_in[1];
  // d_in[2], d_in[3]: triples_* — unused by the reference.
  const void* emb_sr   = d_in[4];
  const void* emb_tg   = d_in[5];
  const int*  edges_sr = (const int*)d_in[6];
  const int*  edges_tg = (const int*)d_in[7];
  const void* W1       = d_in[8];
  const void* W2       = d_in[9];
  float* out = (float*)d_out;

  const int nd = N_ENT_C * DIM_C;  // 12,800,000

  // ws layout (~84 MB of >=102.8 MB proven):
  u16* x_A       = (u16*)d_ws;                    // 25.6 MB (sr)
  u16* x_B       = x_A + (size_t)nd;              // 25.6 MB (tg)
  float* ws_rdeg = (float*)(x_B + (size_t)nd);    // 800 KB (2N)
  int* ws_flag   = (int*)(ws_rdeg + N2_C);        // 256 B
  int* deg       = ws_flag + 64;                  // 800 KB (2N)
  int* row_start = deg + N2_C;                    // 800 KB (2N)
  int* bsum      = row_start + N2_C;              // 4 KB
  int* bkt_cnt   = bsum + 1024;                   // 2 KB
  int2* csr      = (int2*)(bkt_cnt + 512);        // 16 MB  (2M entries {src, rdeg})
  u32* csr_tmp   = (u32*)(csr + (size_t)4 * N_EDGE_C);  // 12.8 MB (391*8192 u32)

  float* out_seed_sr = out;
  float* out_seed_tg = out + (size_t)N_SEED_C * DIM_C;
  float* out_ent_sr  = out + (size_t)2 * N_SEED_C * DIM_C;
  float* out_ent_tg  = out_ent_sr + (size_t)nd;

  // Layer scratch C/D lives in the (dead until k_out_ent) out_ent_sr region:
  // 2 * 25.6 MB bf16 == the 51.2 MB fp32 region exactly.
  u16* x_C = (u16*)out_ent_sr;
  u16* x_D = x_C + (size_t)nd;

  k_detect<<<1, 256, 0, stream>>>((const u32*)emb_sr, ws_flag, bkt_cnt);

  // ---- binned CSR build (both graphs concatenated) ----
  dim3 agrid((N_EDGE_C + EPB - 1) / EPB, 2);      // 123 x 2
  k_fill_binned<<<agrid, 256, 0, stream>>>((const int2*)edges_sr, (const int2*)edges_tg,
                                           bkt_cnt, csr_tmp, N_EDGE_C);
  k_deg<<<NBKT, 256, 0, stream>>>(csr_tmp, bkt_cnt, deg, ws_rdeg);

  const int NB_SCAN = (N2_C + 1023) / 1024;       // 196
  k_scan1<<<NB_SCAN, 256, 0, stream>>>(deg, row_start, bsum, N2_C);
  k_scan2<<<1, 256, 0, stream>>>(bsum, NB_SCAN);
  k_scan3<<<(N2_C + 255) / 256, 256, 0, stream>>>(row_start, bsum, N2_C);

  k_csr_sort<<<NBKT, 256, 0, stream>>>(csr_tmp, bkt_cnt, row_start, ws_rdeg, csr);

  // ---- embeddings -> bf16 (both graphs, one dispatch) ----
  dim3 cgrid((nd / 2 + 255) / 256, 2);
  k_cvt_bf16<<<cgrid, 256, 0, stream>>>(emb_sr, emb_tg, (u32*)x_A, (u32*)x_B, ws_flag, nd / 2);

  // ---- 2 fused GCN layers, both graphs per dispatch ----
  dim3 fgrid(N_ENT_C / 32, 2);                    // 3125 x 2
  // L1: A,B -> C,D
  k_fused<<<fgrid, 256, 0, stream>>>(row_start, deg, csr, (const u32*)x_A, (const u32*)x_B,
                                     ws_rdeg, W1, ws_flag, (u32*)x_C, (u32*)x_D);
  // L2: C,D -> A,B
  k_fused<<<fgrid, 256, 0, stream>>>(row_start, deg, csr, (const u32*)x_C, (const u32*)x_D,
                                     ws_rdeg, W2, ws_flag, (u32*)x_A, (u32*)x_B);

  // ---- outputs (both graphs, batched; overwrite the dead C/D scratch) ----
  dim3 ogrid((nd / 2 + 255) / 256, 2);
  k_out_ent<<<ogrid, 256, 0, stream>>>((const u32*)x_A, (const u32*)x_B,
                                       (float2*)out_ent_sr, (float2*)out_ent_tg, nd / 2);
  dim3 sgrid((N_SEED_C * 64 + 255) / 256, 2);
  k_out_seed<<<sgrid, 256, 0, stream>>>((const u32*)x_A, (const u32*)x_B, sr_seeds, tg_seeds,
                                        (float2*)out_seed_sr, (float2*)out_seed_tg, N_SEED_C * 64);
}

// Round 4
// 553.123 us; speedup vs baseline: 2.3039x; 1.3244x over previous
//
#include <hip/hip_runtime.h>
#include <hip/hip_bf16.h>

#define N_ENT_C   100000
#define N_EDGE_C  500000
#define N_SEED_C  10000
#define DIM_C     128

#define N2_C      (2 * N_ENT_C)     // concat rows (both graphs)
#define NBKT      391               // ceil(N2 / 512)
#define BKT_CAP   8192              // entries per bucket (mean 5120, 43 sigma safe)
#define EPB       4096              // edges per block in phase A

typedef unsigned int   u32;
typedef unsigned short u16;
typedef __attribute__((ext_vector_type(8))) short bf16x8;
typedef __attribute__((ext_vector_type(4))) float f32x4;

__device__ __forceinline__ float bflo(u32 v) { return __uint_as_float(v << 16); }
__device__ __forceinline__ float bfhi(u32 v) { return __uint_as_float(v & 0xFFFF0000u); }
__device__ __forceinline__ u16 f2bf(float f) {       // RNE
  u32 u = __float_as_uint(f);
  u += 0x7FFFu + ((u >> 16) & 1u);
  return (u16)(u >> 16);
}

// Detect fp32 vs packed bf16 input; also zero the bucket counters.
__global__ void k_detect(const u32* __restrict__ words, int* __restrict__ flag,
                         int* __restrict__ bkt_cnt) {
  int tid = threadIdx.x;
  bkt_cnt[tid] = 0;
  bkt_cnt[tid + 256] = 0;
  if (tid == 0) {
    int cnt = 0;
    for (int i = 0; i < 64; ++i) {
      u32 e = (words[i] >> 7) & 0xFF;
      cnt += (e < 96) ? 1 : 0;
    }
    *flag = (cnt >= 8) ? 1 : 0;  // 1 = fp32, 0 = bf16
  }
}

// ---- Phase A: bin edge entries by 512-row bucket into csr_tmp ----
__global__ __launch_bounds__(256, 2) void k_fill_binned(
    const int2* __restrict__ ea, const int2* __restrict__ eb,
    int* __restrict__ bkt_cnt, u32* __restrict__ csr_tmp, int E) {
  __shared__ u32 ein[2 * EPB];        // 32 KB
  __shared__ u16 ebkt[2 * EPB];       // 16 KB
  __shared__ int lcount[512];         // counts, then cursors
  __shared__ int lstart[513];
  __shared__ int gbase[512];
  __shared__ int ssc[256];

  const int tid = threadIdx.x;
  const int gofs = blockIdx.y ? N_ENT_C : 0;
  const int2* ed = blockIdx.y ? eb : ea;
  const int e0 = blockIdx.x * EPB;

  lcount[tid] = 0; lcount[tid + 256] = 0;
  __syncthreads();

  int2 ev[16];
#pragma unroll
  for (int i = 0; i < 16; ++i) {
    int e = e0 + tid + i * 256;
    int2 v = (e < E) ? ed[e] : make_int2(0, 0);
    ev[i] = v;
    if (e < E) {
      atomicAdd(&lcount[(gofs + v.y) >> 9], 1);
      atomicAdd(&lcount[(gofs + v.x) >> 9], 1);
    }
  }
  __syncthreads();

  int a = lcount[2 * tid], b = lcount[2 * tid + 1];
  int ts = a + b;
  ssc[tid] = ts;
  __syncthreads();
  for (int off = 1; off < 256; off <<= 1) {
    int v = (tid >= off) ? ssc[tid - off] : 0;
    __syncthreads();
    ssc[tid] += v;
    __syncthreads();
  }
  int ex = ssc[tid] - ts;
  lstart[2 * tid] = ex;
  lstart[2 * tid + 1] = ex + a;
  if (tid == 255) lstart[512] = ssc[255];
  __syncthreads();

  {
    int b0 = 2 * tid, b1 = 2 * tid + 1;
    if (b0 < NBKT) { int c = lstart[b0 + 1] - lstart[b0]; gbase[b0] = c ? atomicAdd(&bkt_cnt[b0], c) : 0; }
    if (b1 < NBKT) { int c = lstart[b1 + 1] - lstart[b1]; gbase[b1] = c ? atomicAdd(&bkt_cnt[b1], c) : 0; }
    lcount[tid] = lstart[tid];
    lcount[tid + 256] = lstart[tid + 256];
  }
  __syncthreads();

#pragma unroll
  for (int i = 0; i < 16; ++i) {
    int e = e0 + tid + i * 256;
    if (e >= E) continue;
    int2 v = ev[i];
    int r1 = gofs + v.y;
    u32 w1 = (u32)v.x | ((u32)(r1 & 511) << 20);
    int bk1 = r1 >> 9;
    int p = atomicAdd(&lcount[bk1], 1);
    ein[p] = w1; ebkt[p] = (u16)bk1;
    int r2 = gofs + v.x;
    u32 w2 = (u32)v.y | ((u32)(r2 & 511) << 20);
    int bk2 = r2 >> 9;
    p = atomicAdd(&lcount[bk2], 1);
    ein[p] = w2; ebkt[p] = (u16)bk2;
  }
  __syncthreads();

  int tot = lstart[512];
  for (int j = tid; j < tot; j += 256) {
    int bk = ebkt[j];
    u32 off = (u32)(gbase[bk] + (j - lstart[bk]));
    if (off < BKT_CAP) csr_tmp[(size_t)bk * BKT_CAP + off] = ein[j];
  }
}

// ---- Phase B1: per-bucket row counts -> deg + rdeg (coalesced) ----
__global__ void k_deg(const u32* __restrict__ csr_tmp, const int* __restrict__ bkt_cnt,
                      int* __restrict__ deg, float* __restrict__ rdeg) {
  __shared__ int lcnt[512];
  int bk = blockIdx.x, tid = threadIdx.x;
  lcnt[tid] = 0; lcnt[tid + 256] = 0;
  __syncthreads();
  int cnt = min(bkt_cnt[bk], BKT_CAP);
  const u32* src = csr_tmp + (size_t)bk * BKT_CAP;
  for (int j = tid; j < cnt; j += 256)
    atomicAdd(&lcnt[(src[j] >> 20) & 511], 1);
  __syncthreads();
  int rb0 = bk << 9;
  for (int r = tid; r < 512; r += 256) {
    int row = rb0 + r;
    if (row < N2_C) {
      int d = lcnt[r];
      deg[row] = d;
      rdeg[row] = rsqrtf((float)(d + 1));
    }
  }
}

// ---- 3-kernel exclusive scan of deg[n] -> row_start[n] ----
__global__ void k_scan1(const int* __restrict__ deg, int* __restrict__ row_start,
                        int* __restrict__ bsum, int n) {
  __shared__ int s[256];
  int b = blockIdx.x, tid = threadIdx.x;
  int i0 = b * 1024 + tid * 4;
  int d0 = (i0 + 0 < n) ? deg[i0 + 0] : 0;
  int d1 = (i0 + 1 < n) ? deg[i0 + 1] : 0;
  int d2 = (i0 + 2 < n) ? deg[i0 + 2] : 0;
  int d3 = (i0 + 3 < n) ? deg[i0 + 3] : 0;
  int tsum = d0 + d1 + d2 + d3;
  s[tid] = tsum;
  __syncthreads();
  for (int off = 1; off < 256; off <<= 1) {
    int v = (tid >= off) ? s[tid - off] : 0;
    __syncthreads();
    s[tid] += v;
    __syncthreads();
  }
  int toff = s[tid] - tsum;
  if (i0 + 0 < n) row_start[i0 + 0] = toff;
  if (i0 + 1 < n) row_start[i0 + 1] = toff + d0;
  if (i0 + 2 < n) row_start[i0 + 2] = toff + d0 + d1;
  if (i0 + 3 < n) row_start[i0 + 3] = toff + d0 + d1 + d2;
  if (tid == 255) bsum[b] = s[255];
}

__global__ void k_scan2(int* __restrict__ bsum, int nb) {
  __shared__ int s[256];
  int tid = threadIdx.x;
  int v = (tid < nb) ? bsum[tid] : 0;
  s[tid] = v;
  __syncthreads();
  for (int off = 1; off < 256; off <<= 1) {
    int u = (tid >= off) ? s[tid - off] : 0;
    __syncthreads();
    s[tid] += u;
    __syncthreads();
  }
  if (tid < nb) bsum[tid] = s[tid] - v;   // exclusive
}

__global__ void k_scan3(int* __restrict__ row_start, const int* __restrict__ bsum, int n) {
  int i = blockIdx.x * 256 + threadIdx.x;
  if (i < n) row_start[i] += bsum[i >> 10];
}

// ---- Phase B2: sort each bucket into final CSR {src, rdeg[src]} ----
__global__ void k_csr_sort(const u32* __restrict__ csr_tmp, const int* __restrict__ bkt_cnt,
                           const int* __restrict__ row_start, const float* __restrict__ rdeg,
                           int2* __restrict__ csr) {
  __shared__ int lcur[512];
  int bk = blockIdx.x, tid = threadIdx.x;
  int rb0 = bk << 9;
  int base = row_start[rb0];
  for (int r = tid; r < 512; r += 256) {
    int row = rb0 + r;
    lcur[r] = (row < N2_C) ? row_start[row] - base : 0;
  }
  __syncthreads();
  int cnt = min(bkt_cnt[bk], BKT_CAP);
  const u32* srcp = csr_tmp + (size_t)bk * BKT_CAP;
  for (int j = tid; j < cnt; j += 256) {
    u32 w = srcp[j];
    int dl = (w >> 20) & 511;
    int s = w & 0x1FFFF;
    int pos = atomicAdd(&lcur[dl], 1);
    float r = rdeg[((rb0 + dl) >= N_ENT_C ? N_ENT_C : 0) + s];
    csr[base + pos] = make_int2(s, __float_as_int(r));
  }
}

// emb (fp32 or bf16 per flag) -> packed bf16 x. Batched: y=0 -> d0, y=1 -> d1.
__global__ void k_cvt_bf16(const void* __restrict__ s0, const void* __restrict__ s1,
                           u32* __restrict__ d0, u32* __restrict__ d1,
                           const int* __restrict__ flag, int n2) {
  int i = blockIdx.x * 256 + threadIdx.x;
  if (i >= n2) return;
  const void* src = blockIdx.y ? s1 : s0;
  u32* dst = blockIdx.y ? d1 : d0;
  if (*flag) {
    float2 v = ((const float2*)src)[i];
    dst[i] = (u32)f2bf(v.x) | ((u32)f2bf(v.y) << 16);
  } else {
    dst[i] = ((const u32*)src)[i];
  }
}

// 2-entry / 1-entry gather steps
#define G2(cp, t, a0, a1) { \
  int2 e0 = cp[t], e1 = cp[(t) + 1]; \
  u32 v0 = xin[((u32)e0.x << 6) | lane]; \
  u32 v1 = xin[((u32)e1.x << 6) | lane]; \
  float r0 = __int_as_float(e0.y), r1 = __int_as_float(e1.y); \
  a0 += r0 * bflo(v0) + r1 * bflo(v1); \
  a1 += r0 * bfhi(v0) + r1 * bfhi(v1); }
#define G1(cp, t, a0, a1) { \
  int2 e0 = cp[t]; \
  u32 v0 = xin[((u32)e0.x << 6) | lane]; \
  float r0 = __int_as_float(e0.y); \
  a0 += r0 * bflo(v0); a1 += r0 * bfhi(v0); }

// Fused GCN layer. 512 threads (8 waves), 64 rows/block. LDS 48 KB -> 3 blk/CU
// = 24 waves/CU. Gather pairs two rows per wave (2+2 interleaved loads) so one
// row's csr latency hides under the other's xin loads.
// If fout != null: write fp32 directly to out_ent (final layer), no bf16 out.
__global__ __launch_bounds__(512, 6) void k_fused(
    const int* __restrict__ row_start, const int* __restrict__ deg,
    const int2* __restrict__ csr2, const u32* __restrict__ xin0,
    const u32* __restrict__ xin1, const float* __restrict__ rdeg,
    const void* __restrict__ W, const int* __restrict__ flag,
    u32* __restrict__ xout0, u32* __restrict__ xout1,
    float* __restrict__ fout0, float* __restrict__ fout1) {
  __shared__ __align__(16) u16 smem[128 * 128 + 64 * 128];  // 49152 B
  u16* sWt = smem;               // 128x128 bf16 W^T, swizzled
  u16* sA  = smem + 128 * 128;   // 64x128 bf16 A-tile, swizzled

  const int tid = threadIdx.x;
  const int row0 = blockIdx.x * 64;
  const int gofs = blockIdx.y * N_ENT_C;
  const u32* __restrict__ xin  = blockIdx.y ? xin1  : xin0;
  u32* __restrict__ xout       = blockIdx.y ? xout1 : xout0;
  float* __restrict__ fout     = blockIdx.y ? fout1 : fout0;
  const int* rsb = row_start + gofs;
  const int* dgb = deg + gofs;
  const float* rdb = rdeg + gofs;
  const int isf32 = *flag;

  // ---- stage W^T (bf16), swizzled: u32 word (n, k2) at n*64 + (k2 ^ ((n&7)<<2))
  {
    u32* sW32 = (u32*)sWt;
    const float* Wf = (const float*)W;
    const u16*   Wu = (const u16*)W;
    for (int i = tid; i < 64 * 128; i += 512) {
      int k2 = i >> 7;        // pair of k: 2*k2, 2*k2+1
      int n  = i & 127;
      u16 lo, hi;
      if (isf32) { lo = f2bf(Wf[(2 * k2) * 128 + n]); hi = f2bf(Wf[(2 * k2 + 1) * 128 + n]); }
      else       { lo = Wu[(2 * k2) * 128 + n];       hi = Wu[(2 * k2 + 1) * 128 + n]; }
      sW32[n * 64 + (k2 ^ ((n & 7) << 2))] = (u32)lo | ((u32)hi << 16);
    }
  }

  // ---- gather: wave w owns rows [w*8, w*8+8), processed as 4 pairs ----
  const int wave = tid >> 6, lane = tid & 63;
  for (int pq = 0; pq < 4; ++pq) {
    const int rlA = wave * 8 + 2 * pq, rlB = rlA + 1;
    const int rowA = row0 + rlA, rowB = row0 + rlB;
    const bool vA = rowA < N_ENT_C, vB = rowB < N_ENT_C;
    int rsA = vA ? rsb[rowA] : 0, deA = vA ? dgb[rowA] : 0;
    int rsB = vB ? rsb[rowB] : 0, deB = vB ? dgb[rowB] : 0;
    rsA = __builtin_amdgcn_readfirstlane(rsA); deA = __builtin_amdgcn_readfirstlane(deA);
    rsB = __builtin_amdgcn_readfirstlane(rsB); deB = __builtin_amdgcn_readfirstlane(deB);
    const float rdA = vA ? rdb[rowA] : 0.f, rdB = vB ? rdb[rowB] : 0.f;
    const u32 vsA = vA ? xin[((u32)rowA << 6) | lane] : 0u;
    const u32 vsB = vB ? xin[((u32)rowB << 6) | lane] : 0u;
    const int2* cA = csr2 + rsA;
    const int2* cB = csr2 + rsB;
    float a0A = 0.f, a1A = 0.f, a0B = 0.f, a1B = 0.f;
    int tA = 0, tB = 0;
    // joint phase: two independent chains, 4 xin loads in flight
    while (tA + 1 < deA && tB + 1 < deB) {
      int2 eA0 = cA[tA], eA1 = cA[tA + 1];
      int2 eB0 = cB[tB], eB1 = cB[tB + 1];
      u32 uA0 = xin[((u32)eA0.x << 6) | lane];
      u32 uA1 = xin[((u32)eA1.x << 6) | lane];
      u32 uB0 = xin[((u32)eB0.x << 6) | lane];
      u32 uB1 = xin[((u32)eB1.x << 6) | lane];
      float rA0 = __int_as_float(eA0.y), rA1 = __int_as_float(eA1.y);
      float rB0 = __int_as_float(eB0.y), rB1 = __int_as_float(eB1.y);
      a0A += rA0 * bflo(uA0) + rA1 * bflo(uA1);
      a1A += rA0 * bfhi(uA0) + rA1 * bfhi(uA1);
      a0B += rB0 * bflo(uB0) + rB1 * bflo(uB1);
      a1B += rB0 * bfhi(uB0) + rB1 * bfhi(uB1);
      tA += 2; tB += 2;
    }
    // drains (one of the two rows typically has entries left)
    for (; tA + 3 < deA; tA += 4) { G2(cA, tA, a0A, a1A); G2(cA, tA + 2, a0A, a1A); }
    if (tA + 1 < deA) { G2(cA, tA, a0A, a1A); tA += 2; }
    if (tA < deA) G1(cA, tA, a0A, a1A);
    for (; tB + 3 < deB; tB += 4) { G2(cB, tB, a0B, a1B); G2(cB, tB + 2, a0B, a1B); }
    if (tB + 1 < deB) { G2(cB, tB, a0B, a1B); tB += 2; }
    if (tB < deB) G1(cB, tB, a0B, a1B);

    a0A = rdA * a0A + rdA * rdA * bflo(vsA);
    a1A = rdA * a1A + rdA * rdA * bfhi(vsA);
    a0B = rdB * a0B + rdB * rdB * bflo(vsB);
    a1B = rdB * a1B + rdB * rdB * bfhi(vsB);
    ((u32*)sA)[rlA * 64 + (lane ^ ((rlA & 7) << 2))] = (u32)f2bf(a0A) | ((u32)f2bf(a1A) << 16);
    ((u32*)sA)[rlB * 64 + (lane ^ ((rlB & 7) << 2))] = (u32)f2bf(a0B) | ((u32)f2bf(a1B) << 16);
  }
  __syncthreads();

  // ---- MFMA: 8 waves, wave -> 16 rows x 64 cols ----
  const int rows_h = (wave >> 1) * 16;   // 0 | 16 | 32 | 48
  const int col_q  = (wave & 1) * 64;    // 0 | 64
  const int m = lane & 15, q = lane >> 4;
  f32x4 acc[4];
  for (int ct = 0; ct < 4; ++ct) acc[ct] = (f32x4){0.f, 0.f, 0.f, 0.f};
#pragma unroll
  for (int kt = 0; kt < 4; ++kt) {
    int k0 = kt * 32 + q * 8;
    int ks = k0 ^ ((m & 7) << 3);        // same swizzle for A row and W^T rows
    bf16x8 a = *(const bf16x8*)&sA[(rows_h + m) * 128 + ks];
#pragma unroll
    for (int ct = 0; ct < 4; ++ct) {
      bf16x8 b = *(const bf16x8*)&sWt[(col_q + ct * 16 + m) * 128 + ks];
      acc[ct] = __builtin_amdgcn_mfma_f32_16x16x32_bf16(a, b, acc[ct], 0, 0, 0);
    }
  }
  __syncthreads();   // all waves done reading sWt/sA before C overwrites smem

  // ---- C (fp32) into LDS for coalesced epilogue ----
  float* sC = (float*)smem;              // 64 x 132 fp32 = 33792 B (fits 48 KB)
#pragma unroll
  for (int ct = 0; ct < 4; ++ct)
#pragma unroll
    for (int r = 0; r < 4; ++r)
      sC[(rows_h + q * 4 + r) * 132 + (col_q + ct * 16 + m)] = acc[ct][r];
  __syncthreads();

  // ---- epilogue: +residual, relu; fp32 direct out (final) or bf16 pack ----
  {
    int rowl = tid >> 3;                 // 0..63
    int c0 = (tid & 7) * 16;
    int row = row0 + rowl;
    if (row < N_ENT_C) {
      size_t goff = (size_t)row * 64 + (c0 >> 1);  // in u32 units
      const u32* resp = xin + goff;
      if (fout) {
        float* op = fout + (size_t)row * 128 + c0;
#pragma unroll
        for (int u2 = 0; u2 < 4; ++u2) {
          u32 rv0 = resp[2 * u2], rv1 = resp[2 * u2 + 1];
          f32x4 f;
          f[0] = fmaxf(sC[rowl * 132 + c0 + 4 * u2    ] + bflo(rv0), 0.f);
          f[1] = fmaxf(sC[rowl * 132 + c0 + 4 * u2 + 1] + bfhi(rv0), 0.f);
          f[2] = fmaxf(sC[rowl * 132 + c0 + 4 * u2 + 2] + bflo(rv1), 0.f);
          f[3] = fmaxf(sC[rowl * 132 + c0 + 4 * u2 + 3] + bfhi(rv1), 0.f);
          __builtin_nontemporal_store(f, (f32x4*)(op + 4 * u2));
        }
      } else {
        u32 ov[8];
#pragma unroll
        for (int u = 0; u < 8; ++u) {
          u32 rv = resp[u];
          float lo = fmaxf(sC[rowl * 132 + c0 + 2 * u]     + bflo(rv), 0.f);
          float hi = fmaxf(sC[rowl * 132 + c0 + 2 * u + 1] + bfhi(rv), 0.f);
          ov[u] = (u32)f2bf(lo) | ((u32)f2bf(hi) << 16);
        }
        uint4* op = (uint4*)(xout + goff);
        op[0] = make_uint4(ov[0], ov[1], ov[2], ov[3]);
        op[1] = make_uint4(ov[4], ov[5], ov[6], ov[7]);
      }
    }
  }
}

// Seed outputs: copy fp32 rows from out_ent (already final fp32).
__global__ void k_out_seed(const float4* __restrict__ ea, const float4* __restrict__ eb,
                           const int* __restrict__ sa, const int* __restrict__ sb,
                           float4* __restrict__ oa, float4* __restrict__ ob, int total4) {
  int t = blockIdx.x * 256 + threadIdx.x;
  if (t >= total4) return;
  const float4* e = blockIdx.y ? eb : ea;
  const int* seeds = blockIdx.y ? sb : sa;
  float4* o = blockIdx.y ? ob : oa;
  int s = t >> 5, w = t & 31;            // 32 float4 per row
  o[t] = e[((size_t)seeds[s] << 5) | w];
}

extern "C" void kernel_launch(void* const* d_in, const int* in_sizes, int n_in,
                              void* d_out, int out_size, void* d_ws, size_t ws_size,
                              hipStream_t stream) {
  const int*  sr_seeds = (const int*)d_in[0];
  const int*  tg_seeds = (const int*)d_in[1];
  // d_in[2], d_in[3]: triples_* — unused by the reference.
  const void* emb_sr   = d_in[4];
  const void* emb_tg   = d_in[5];
  const int*  edges_sr = (const int*)d_in[6];
  const int*  edges_tg = (const int*)d_in[7];
  const void* W1       = d_in[8];
  const void* W2       = d_in[9];
  float* out = (float*)d_out;

  const int nd = N_ENT_C * DIM_C;  // 12,800,000

  // ws layout (~95.2 MB of >=102.8 MB proven):
  u16* x_A       = (u16*)d_ws;                    // 25.6 MB (cvt out sr, L1 in)
  u16* x_B       = x_A + (size_t)nd;              // 25.6 MB (cvt out tg, L1 in)
  float* ws_rdeg = (float*)(x_B + (size_t)nd);    // 800 KB (2N)
  int* ws_flag   = (int*)(ws_rdeg + N2_C);        // 256 B
  int* deg       = ws_flag + 64;                  // 800 KB (2N)
  int* row_start = deg + N2_C;                    // 800 KB (2N)
  int* bsum      = row_start + N2_C;              // 4 KB
  int* bkt_cnt   = bsum + 1024;                   // 2 KB
  int2* csr      = (int2*)(bkt_cnt + 512);        // 16 MB  (2M entries {src, rdeg})
  u32* csr_tmp   = (u32*)(csr + (size_t)4 * N_EDGE_C);  // 12.8 MB, dead after sort
  u16* x_C       = (u16*)csr_tmp;                 // 25.6 MB overlay (L1 out sr, L2 in)

  float* out_seed_sr = out;
  float* out_seed_tg = out + (size_t)N_SEED_C * DIM_C;
  float* out_ent_sr  = out + (size_t)2 * N_SEED_C * DIM_C;
  float* out_ent_tg  = out_ent_sr + (size_t)nd;

  // x_D (L1 out tg) lives in out_ent_sr region; consumed by L2-tg BEFORE
  // L2-sr overwrites that region with fp32 (in-order stream).
  u16* x_D = (u16*)out_ent_sr;

  k_detect<<<1, 256, 0, stream>>>((const u32*)emb_sr, ws_flag, bkt_cnt);

  // ---- binned CSR build (both graphs concatenated) ----
  dim3 agrid((N_EDGE_C + EPB - 1) / EPB, 2);      // 123 x 2
  k_fill_binned<<<agrid, 256, 0, stream>>>((const int2*)edges_sr, (const int2*)edges_tg,
                                           bkt_cnt, csr_tmp, N_EDGE_C);
  k_deg<<<NBKT, 256, 0, stream>>>(csr_tmp, bkt_cnt, deg, ws_rdeg);

  const int NB_SCAN = (N2_C + 1023) / 1024;       // 196
  k_scan1<<<NB_SCAN, 256, 0, stream>>>(deg, row_start, bsum, N2_C);
  k_scan2<<<1, 256, 0, stream>>>(bsum, NB_SCAN);
  k_scan3<<<(N2_C + 255) / 256, 256, 0, stream>>>(row_start, bsum, N2_C);

  k_csr_sort<<<NBKT, 256, 0, stream>>>(csr_tmp, bkt_cnt, row_start, ws_rdeg, csr);

  // ---- embeddings -> bf16 (both graphs, one dispatch) ----
  dim3 cgrid((nd / 2 + 255) / 256, 2);
  k_cvt_bf16<<<cgrid, 256, 0, stream>>>(emb_sr, emb_tg, (u32*)x_A, (u32*)x_B, ws_flag, nd / 2);

  const int NBF = (N_ENT_C + 63) / 64;            // 1563

  // ---- L1: A,B -> C,D (bf16), both graphs in one dispatch ----
  dim3 f2grid(NBF, 2);
  k_fused<<<f2grid, 512, 0, stream>>>(row_start, deg, csr, (const u32*)x_A, (const u32*)x_B,
                                      ws_rdeg, W1, ws_flag, (u32*)x_C, (u32*)x_D,
                                      nullptr, nullptr);

  // ---- L2-tg first (reads x_D in out_ent_sr region), writes fp32 out_ent_tg ----
  k_fused<<<dim3(NBF, 1), 512, 0, stream>>>(row_start + N_ENT_C, deg + N_ENT_C, csr,
                                            (const u32*)x_D, nullptr, ws_rdeg + N_ENT_C,
                                            W2, ws_flag, nullptr, nullptr,
                                            out_ent_tg, nullptr);
  // ---- L2-sr: reads x_C (ws), writes fp32 out_ent_sr (clobbers dead x_D) ----
  k_fused<<<dim3(NBF, 1), 512, 0, stream>>>(row_start, deg, csr,
                                            (const u32*)x_C, nullptr, ws_rdeg,
                                            W2, ws_flag, nullptr, nullptr,
                                            out_ent_sr, nullptr);

  // ---- seed outputs: fp32 row copies from out_ent ----
  dim3 sgrid((N_SEED_C * 32 + 255) / 256, 2);
  k_out_seed<<<sgrid, 256, 0, stream>>>((const float4*)out_ent_sr, (const float4*)out_ent_tg,
                                        sr_seeds, tg_seeds,
                                        (float4*)out_seed_sr, (float4*)out_seed_tg,
                                        N_SEED_C * 32);
}